// Round 15
// baseline (1083.970 us; speedup 1.0000x reference)
//
#include <hip/hip_runtime.h>

#define N_NODES 100000
#define N_EDGES 1600000
#define DIM 64
#define NLAYERS 5
#define NUM_GRAPHS 256
#define BN_EPS 1e-5f
#define STATS_BLOCKS 1024   /* was 256 = 1 block/CU = 12.5% occupancy; 1024 -> 4 blocks/CU */
#define CSR_CAP 32
#define OV_CAP 65536
#define NSHARD 4
#define SHARD_W (N_NODES / NSHARD)     /* 25000 */
#define NBLK ((N_NODES + 255) / 256)   /* 391 */

typedef _Float16 f16;
typedef _Float16 f16x4 __attribute__((ext_vector_type(4)));

// ---------------------------------------------------------------------------
// CSR build, sharded by target range (R4: full-range scatter writes thrashed
// 8 private L2s -> 96MB WRITE_SIZE; 3.2MB dirty footprint/pass merges in L2).
// ---------------------------------------------------------------------------
__global__ __launch_bounds__(256) void build_csr_shard_kernel(
        const int* __restrict__ ei, int* __restrict__ cursor,
        int* __restrict__ csr, int* __restrict__ ovcnt, int* __restrict__ ovpairs,
        int lo, int hi) {
    int e = blockIdx.x * 256 + threadIdx.x;
    if (e >= N_EDGES) return;
    int t = ei[N_EDGES + e];
    if (t < lo || t >= hi) return;
    int s = ei[e];
    int c = atomicAdd(&cursor[t], 1);
    if (c < CSR_CAP) {
        csr[t * CSR_CAP + c] = s;
    } else {
        int o = atomicAdd(ovcnt, 1);
        if (o < OV_CAP) { ovpairs[2 * o] = t; ovpairs[2 * o + 1] = s; }
    }
}

// fp16 copy of x for layer 0's gathers (4 elems/thread, coalesced).
__global__ void cast_x_kernel(const float* __restrict__ x, f16* __restrict__ h16) {
    long t = (long)blockIdx.x * 256 + threadIdx.x;
    if (t >= (long)N_NODES * DIM / 4) return;
    float4 v = ((const float4*)x)[t];
    f16x4 p = { (f16)v.x, (f16)v.y, (f16)v.z, (f16)v.w };
    *(f16x4*)(h16 + t * 4) = p;
}

// ---------------------------------------------------------------------------
// fp16-gather aggregate (R9 form, measured-best): wave = node, lane = dim;
// each neighbor row = ONE fully-used 128B line request; 8 lines in flight;
// f32 accumulate; self term from exact f32 activations.
// ---------------------------------------------------------------------------
__global__ __launch_bounds__(256) void aggregate_f16_kernel(
        const int* __restrict__ csr, const int* __restrict__ deg,
        const int* __restrict__ ovcnt, const int* __restrict__ ovpairs,
        const f16* __restrict__ h16, const float* __restrict__ hself, int hstride,
        float* __restrict__ agg) {
    long tid = (long)blockIdx.x * 256 + threadIdx.x;
    int n = (int)(tid >> 6);
    int d = (int)(tid & 63);
    if (n >= N_NODES) return;
    int dval = deg[n];
    int cnt = min(dval, CSR_CAP);
    const int4* row = (const int4*)(csr + n * CSR_CAP);  // 128B-aligned
    float own = hself[(long)n * hstride + d];
    float a0 = 0.f, a1 = 0.f, a2 = 0.f, a3 = 0.f;
    float a4 = 0.f, a5 = 0.f, a6 = 0.f, a7 = 0.f;
    for (int k = 0; k < cnt; k += 8) {
        int4 ra = row[k >> 2];
        int4 rb = row[(k >> 2) + 1];
        int s0 = (k + 0 < cnt) ? ra.x : 0;   // clamp -> hot node-0 line
        int s1 = (k + 1 < cnt) ? ra.y : 0;
        int s2 = (k + 2 < cnt) ? ra.z : 0;
        int s3 = (k + 3 < cnt) ? ra.w : 0;
        int s4 = (k + 4 < cnt) ? rb.x : 0;
        int s5 = (k + 5 < cnt) ? rb.y : 0;
        int s6 = (k + 6 < cnt) ? rb.z : 0;
        int s7 = (k + 7 < cnt) ? rb.w : 0;
        float v0 = (float)h16[(long)s0 * DIM + d];   // 128B/wave, 1 line req
        float v1 = (float)h16[(long)s1 * DIM + d];
        float v2 = (float)h16[(long)s2 * DIM + d];
        float v3 = (float)h16[(long)s3 * DIM + d];
        float v4 = (float)h16[(long)s4 * DIM + d];
        float v5 = (float)h16[(long)s5 * DIM + d];
        float v6 = (float)h16[(long)s6 * DIM + d];
        float v7 = (float)h16[(long)s7 * DIM + d];
        a0 += (k + 0 < cnt) ? v0 : 0.f;
        a1 += (k + 1 < cnt) ? v1 : 0.f;
        a2 += (k + 2 < cnt) ? v2 : 0.f;
        a3 += (k + 3 < cnt) ? v3 : 0.f;
        a4 += (k + 4 < cnt) ? v4 : 0.f;
        a5 += (k + 5 < cnt) ? v5 : 0.f;
        a6 += (k + 6 < cnt) ? v6 : 0.f;
        a7 += (k + 7 < cnt) ? v7 : 0.f;
    }
    if (dval > CSR_CAP) {                 // rare overflow edges
        int m = min(*ovcnt, OV_CAP);
        for (int i = 0; i < m; ++i) {
            if (ovpairs[2 * i] == n) a0 += (float)h16[(long)ovpairs[2 * i + 1] * DIM + d];
        }
    }
    agg[(long)n * DIM + d] = own + ((a0 + a1) + (a2 + a3)) + ((a4 + a5) + (a6 + a7));
}

// ---------------------------------------------------------------------------
// out[n] = relu(in[n] @ W + b). 2 nodes x 32 dims per thread (R9 form,
// measured-best): 64 acc + light staging stays well under the VGPR cliff
// (R3/R11/R12 all spilled with heavier structures); sW reads are wave-uniform
// broadcasts (conflict-free).
// ---------------------------------------------------------------------------
__global__ __launch_bounds__(256) void mlp_gemm_kernel(
        const float* __restrict__ in, const float* __restrict__ W,
        const float* __restrict__ b, float* __restrict__ out) {
    __shared__ __align__(16) float sW[DIM * DIM];
    __shared__ float sb[DIM];
    for (int k = threadIdx.x; k < DIM * DIM / 4; k += 256)
        ((float4*)sW)[k] = ((const float4*)W)[k];
    if (threadIdx.x < DIM) sb[threadIdx.x] = b[threadIdx.x];
    __syncthreads();

    int p = threadIdx.x & 127;
    int j0 = (threadIdx.x >> 7) * 32;
    int base = blockIdx.x * 256;
    int n0 = base + p;
    int n1 = base + 128 + p;
    bool v1 = n1 < N_NODES;
    const float* inr0 = in + (long)n0 * DIM;
    const float* inr1 = in + (long)(v1 ? n1 : n0) * DIM;

    float acc0[32], acc1[32];
#pragma unroll
    for (int j = 0; j < 32; ++j) { acc0[j] = sb[j0 + j]; acc1[j] = acc0[j]; }

    for (int d4 = 0; d4 < DIM / 4; ++d4) {
        float4 za = ((const float4*)inr0)[d4];
        float4 zb = ((const float4*)inr1)[d4];
        const float* w0 = sW + (d4 * 4 + 0) * DIM + j0;
        const float* w1 = sW + (d4 * 4 + 1) * DIM + j0;
        const float* w2 = sW + (d4 * 4 + 2) * DIM + j0;
        const float* w3 = sW + (d4 * 4 + 3) * DIM + j0;
#pragma unroll
        for (int j = 0; j < 32; j += 4) {
            float4 a0 = *(const float4*)(w0 + j);
            float4 a1 = *(const float4*)(w1 + j);
            float4 a2 = *(const float4*)(w2 + j);
            float4 a3 = *(const float4*)(w3 + j);
            acc0[j + 0] += za.x * a0.x + za.y * a1.x + za.z * a2.x + za.w * a3.x;
            acc0[j + 1] += za.x * a0.y + za.y * a1.y + za.z * a2.y + za.w * a3.y;
            acc0[j + 2] += za.x * a0.z + za.y * a1.z + za.z * a2.z + za.w * a3.z;
            acc0[j + 3] += za.x * a0.w + za.y * a1.w + za.z * a2.w + za.w * a3.w;
            acc1[j + 0] += zb.x * a0.x + zb.y * a1.x + zb.z * a2.x + zb.w * a3.x;
            acc1[j + 1] += zb.x * a0.y + zb.y * a1.y + zb.z * a2.y + zb.w * a3.y;
            acc1[j + 2] += zb.x * a0.z + zb.y * a1.z + zb.z * a2.z + zb.w * a3.z;
            acc1[j + 3] += zb.x * a0.w + zb.y * a1.w + zb.z * a2.w + zb.w * a3.w;
        }
    }

    float* o0 = out + (long)n0 * DIM + j0;
#pragma unroll
    for (int j = 0; j < 32; j += 4) {
        float4 v = { fmaxf(acc0[j], 0.f), fmaxf(acc0[j + 1], 0.f),
                     fmaxf(acc0[j + 2], 0.f), fmaxf(acc0[j + 3], 0.f) };
        *(float4*)(o0 + j) = v;
    }
    if (v1) {
        float* o1 = out + (long)n1 * DIM + j0;
#pragma unroll
        for (int j = 0; j < 32; j += 4) {
            float4 v = { fmaxf(acc1[j], 0.f), fmaxf(acc1[j + 1], 0.f),
                         fmaxf(acc1[j + 2], 0.f), fmaxf(acc1[j + 3], 0.f) };
            *(float4*)(o1 + j) = v;
        }
    }
}

// ---------------------------------------------------------------------------
// BN stats: per-block partial (sum, sumsq) per dim, unrolled x4; finalize.
// STATS_BLOCKS=1024: 4 blocks/CU (was 1) -> 4x lines in flight, latency-bound
// strided reads now covered.
// ---------------------------------------------------------------------------
__global__ void stats_partial_kernel(const float* __restrict__ z, float* __restrict__ partials) {
    __shared__ float red[2 * 256];
    int d = threadIdx.x & 63;
    int slot = threadIdx.x >> 6;
    const int S = STATS_BLOCKS * 4;  // 4096
    float s1 = 0.f, s2 = 0.f;
    int n = blockIdx.x * 4 + slot;
    for (; n + 3 * S < N_NODES; n += 4 * S) {
        float v0 = z[(long)(n + 0 * S) * DIM + d];
        float v1 = z[(long)(n + 1 * S) * DIM + d];
        float v2 = z[(long)(n + 2 * S) * DIM + d];
        float v3 = z[(long)(n + 3 * S) * DIM + d];
        s1 += v0 + v1 + v2 + v3;
        s2 += v0 * v0 + v1 * v1 + v2 * v2 + v3 * v3;
    }
    for (; n < N_NODES; n += S) {
        float v = z[(long)n * DIM + d];
        s1 += v;
        s2 += v * v;
    }
    red[threadIdx.x] = s1;
    red[256 + threadIdx.x] = s2;
    __syncthreads();
    if (threadIdx.x < 64) {
        float a = red[d] + red[64 + d] + red[128 + d] + red[192 + d];
        float c = red[256 + d] + red[320 + d] + red[384 + d] + red[448 + d];
        partials[blockIdx.x * 128 + d] = a;
        partials[blockIdx.x * 128 + 64 + d] = c;
    }
}

__global__ void stats_finalize_kernel(const float* __restrict__ partials,
                                      const float* __restrict__ gamma,
                                      const float* __restrict__ beta,
                                      float* __restrict__ ss) {
    __shared__ float r1[256], r2[256];
    int d = threadIdx.x & 63, q = threadIdx.x >> 6;
    float s1 = 0.f, s2 = 0.f;
    for (int b2_ = q; b2_ < STATS_BLOCKS; b2_ += 4) {
        s1 += partials[b2_ * 128 + d];
        s2 += partials[b2_ * 128 + 64 + d];
    }
    r1[threadIdx.x] = s1;
    r2[threadIdx.x] = s2;
    __syncthreads();
    if (threadIdx.x < 64) {
        s1 = r1[d] + r1[64 + d] + r1[128 + d] + r1[192 + d];
        s2 = r2[d] + r2[64 + d] + r2[128 + d] + r2[192 + d];
        float mu = s1 * (1.f / N_NODES);
        float var = s2 * (1.f / N_NODES) - mu * mu;
        float rs = 1.f / sqrtf(fmaxf(var, 0.f) + BN_EPS);
        float sc = gamma[d] * rs;
        ss[d] = sc;
        ss[64 + d] = beta[d] - mu * sc;
    }
}

// z_bn = z*scale + shift into xs slice (row stride 320) AND the fp16 gather
// copy for the next layer (h16 == nullptr on last layer).
__global__ void bn_apply_kernel(const float* __restrict__ z, const float* __restrict__ ss,
                                float* __restrict__ outxs, f16* __restrict__ h16) {
    long t = (long)blockIdx.x * 256 + threadIdx.x;
    if (t >= (long)N_NODES * (DIM / 4)) return;
    int r = (int)(t & 15);
    long n = t >> 4;
    float4 v = ((const float4*)(z + n * DIM))[r];
    float4 sc = ((const float4*)ss)[r];
    float4 sh = ((const float4*)(ss + DIM))[r];
    float4 o = { v.x * sc.x + sh.x, v.y * sc.y + sh.y,
                 v.z * sc.z + sh.z, v.w * sc.w + sh.w };
    ((float4*)(outxs + n * (DIM * NLAYERS)))[r] = o;
    if (h16) {
        f16x4 p = { (f16)o.x, (f16)o.y, (f16)o.z, (f16)o.w };
        *(f16x4*)(h16 + n * DIM + r * 4) = p;
    }
}

__global__ void graph_starts_kernel(const int* __restrict__ batch, int* __restrict__ starts) {
    int g = threadIdx.x;
    if (g > NUM_GRAPHS) return;
    int lo = 0, hi = N_NODES;
    while (lo < hi) {
        int mid = (lo + hi) >> 1;
        if (batch[mid] < g) lo = mid + 1; else hi = mid;
    }
    starts[g] = lo;
}

// Pool: block = (graph, layer-slice of 64 dims); 1280 one-wave blocks.
__global__ __launch_bounds__(64) void pool_kernel(
        const float* __restrict__ xs, const int* __restrict__ starts,
        float* __restrict__ outpool) {
    int g = blockIdx.x;
    int d = blockIdx.y * 64 + threadIdx.x;
    int s = starts[g], e = starts[g + 1];
    const int LD = DIM * NLAYERS;
    float a0 = 0.f, a1 = 0.f, a2 = 0.f, a3 = 0.f;
    float a4 = 0.f, a5 = 0.f, a6 = 0.f, a7 = 0.f;
    int n = s;
    for (; n + 8 <= e; n += 8) {
        a0 += xs[(long)(n + 0) * LD + d];
        a1 += xs[(long)(n + 1) * LD + d];
        a2 += xs[(long)(n + 2) * LD + d];
        a3 += xs[(long)(n + 3) * LD + d];
        a4 += xs[(long)(n + 4) * LD + d];
        a5 += xs[(long)(n + 5) * LD + d];
        a6 += xs[(long)(n + 6) * LD + d];
        a7 += xs[(long)(n + 7) * LD + d];
    }
    for (; n < e; ++n) a0 += xs[(long)n * LD + d];
    float acc = ((a0 + a1) + (a2 + a3)) + ((a4 + a5) + (a6 + a7));
    outpool[(long)g * LD + d] = acc / fmaxf((float)(e - s), 1.f);
}

// ---------------------------------------------------------------------------
static inline size_t rup(size_t x) { return (x + 255) & ~(size_t)255; }

extern "C" void kernel_launch(void* const* d_in, const int* in_sizes, int n_in,
                              void* d_out, int out_size, void* d_ws, size_t ws_size,
                              hipStream_t stream) {
    const float* x     = (const float*)d_in[0];
    const int*   ei    = (const int*)d_in[1];
    const int*   batch = (const int*)d_in[2];
    const float* W1    = (const float*)d_in[3];
    const float* b1    = (const float*)d_in[4];
    const float* W2    = (const float*)d_in[5];
    const float* b2    = (const float*)d_in[6];
    const float* gamma = (const float*)d_in[7];
    const float* beta  = (const float*)d_in[8];

    float* out      = (float*)d_out;
    float* out_pool = out;                                      // 256 x 320
    float* out_xs   = out + (size_t)NUM_GRAPHS * DIM * NLAYERS; // 100000 x 320

    char* w = (char*)d_ws;
    int*   csr      = (int*)w;    w += rup((size_t)N_NODES * CSR_CAP * 4);
    int*   cursor   = (int*)w;    w += rup((size_t)N_NODES * 4);
    int*   ovcnt    = (int*)w;    w += 256;
    int*   ovpairs  = (int*)w;    w += rup((size_t)OV_CAP * 8);
    float* agg      = (float*)w;  w += rup((size_t)N_NODES * DIM * 4);
    float* bufB     = (float*)w;  w += rup((size_t)N_NODES * DIM * 4);
    f16*   h16      = (f16*)w;    w += rup((size_t)N_NODES * DIM * 2);
    float* partials = (float*)w;  w += rup((size_t)STATS_BLOCKS * 128 * 4);
    float* ss       = (float*)w;  w += 512;
    int*   starts   = (int*)w;    w += rup((size_t)(NUM_GRAPHS + 1) * 4);
    float* zbuf     = agg;        // gemm2 output reuses agg

    hipMemsetAsync(cursor, 0, (size_t)N_NODES * 4, stream);
    hipMemsetAsync(ovcnt, 0, 4, stream);
    for (int sh = 0; sh < NSHARD; ++sh) {
        build_csr_shard_kernel<<<(N_EDGES + 255) / 256, 256, 0, stream>>>(
            ei, cursor, csr, ovcnt, ovpairs, sh * SHARD_W, (sh + 1) * SHARD_W);
    }
    cast_x_kernel<<<((long)N_NODES * DIM / 4 + 255) / 256, 256, 0, stream>>>(x, h16);
    graph_starts_kernel<<<1, 320, 0, stream>>>(batch, starts);

    const float* hself = x;
    int hs = DIM;
    for (int l = 0; l < NLAYERS; ++l) {
        // agg = hself + neighbor-sum(h16)   (f32 accum, fp16 gather, 1 node/wave)
        aggregate_f16_kernel<<<((long)N_NODES * DIM + 255) / 256, 256, 0, stream>>>(
            csr, cursor, ovcnt, ovpairs, h16, hself, hs, agg);
        // bufB = relu(agg @ W1 + b1)
        mlp_gemm_kernel<<<NBLK, 256, 0, stream>>>(
            agg, W1 + (size_t)l * DIM * DIM, b1 + (size_t)l * DIM, bufB);
        // zbuf = relu(bufB @ W2 + b2)   (overwrites agg)
        mlp_gemm_kernel<<<NBLK, 256, 0, stream>>>(
            bufB, W2 + (size_t)l * DIM * DIM, b2 + (size_t)l * DIM, zbuf);
        stats_partial_kernel<<<STATS_BLOCKS, 256, 0, stream>>>(zbuf, partials);
        stats_finalize_kernel<<<1, 256, 0, stream>>>(partials, gamma + (size_t)l * DIM,
                                                     beta + (size_t)l * DIM, ss);
        bn_apply_kernel<<<((long)N_NODES * (DIM / 4) + 255) / 256, 256, 0, stream>>>(
            zbuf, ss, out_xs + (size_t)l * DIM, (l + 1 < NLAYERS) ? h16 : nullptr);
        hself = out_xs + (size_t)l * DIM;
        hs = DIM * NLAYERS;
    }

    pool_kernel<<<dim3(NUM_GRAPHS, NLAYERS), 64, 0, stream>>>(out_xs, starts, out_pool);
}

// Round 17
// 850.922 us; speedup vs baseline: 1.2739x; 1.2739x over previous
//
#include <hip/hip_runtime.h>

#define N_NODES 100000
#define N_EDGES 1600000
#define DIM 64
#define NLAYERS 5
#define NUM_GRAPHS 256
#define BN_EPS 1e-5f
#define STATS_BLOCKS 256
#define CSR_CAP 32
#define OV_CAP 65536
#define NSHARD 4
#define SHARD_W (N_NODES / NSHARD)     /* 25000 */
#define NBLK ((N_NODES + 255) / 256)   /* 391 */

typedef _Float16 f16;
typedef _Float16 f16x4 __attribute__((ext_vector_type(4)));

// ---------------------------------------------------------------------------
// CSR build, sharded by target range (R4: full-range scatter writes thrashed
// 8 private L2s -> 96MB WRITE_SIZE; 3.2MB dirty footprint/pass merges in L2).
// ---------------------------------------------------------------------------
__global__ __launch_bounds__(256) void build_csr_shard_kernel(
        const int* __restrict__ ei, int* __restrict__ cursor,
        int* __restrict__ csr, int* __restrict__ ovcnt, int* __restrict__ ovpairs,
        int lo, int hi) {
    int e = blockIdx.x * 256 + threadIdx.x;
    if (e >= N_EDGES) return;
    int t = ei[N_EDGES + e];
    if (t < lo || t >= hi) return;
    int s = ei[e];
    int c = atomicAdd(&cursor[t], 1);
    if (c < CSR_CAP) {
        csr[t * CSR_CAP + c] = s;
    } else {
        int o = atomicAdd(ovcnt, 1);
        if (o < OV_CAP) { ovpairs[2 * o] = t; ovpairs[2 * o + 1] = s; }
    }
}

// fp16 copy of x for layer 0's gathers (4 elems/thread, coalesced).
__global__ void cast_x_kernel(const float* __restrict__ x, f16* __restrict__ h16) {
    long t = (long)blockIdx.x * 256 + threadIdx.x;
    if (t >= (long)N_NODES * DIM / 4) return;
    float4 v = ((const float4*)x)[t];
    f16x4 p = { (f16)v.x, (f16)v.y, (f16)v.z, (f16)v.w };
    *(f16x4*)(h16 + t * 4) = p;
}

// ---------------------------------------------------------------------------
// fp16-gather aggregate (R9 form, measured-best): wave = node, lane = dim;
// each neighbor row = ONE fully-used 128B line request; 8 lines in flight;
// f32 accumulate; self term from exact f32 activations.
// ---------------------------------------------------------------------------
__global__ __launch_bounds__(256) void aggregate_f16_kernel(
        const int* __restrict__ csr, const int* __restrict__ deg,
        const int* __restrict__ ovcnt, const int* __restrict__ ovpairs,
        const f16* __restrict__ h16, const float* __restrict__ hself, int hstride,
        float* __restrict__ agg) {
    long tid = (long)blockIdx.x * 256 + threadIdx.x;
    int n = (int)(tid >> 6);
    int d = (int)(tid & 63);
    if (n >= N_NODES) return;
    int dval = deg[n];
    int cnt = min(dval, CSR_CAP);
    const int4* row = (const int4*)(csr + n * CSR_CAP);  // 128B-aligned
    float own = hself[(long)n * hstride + d];
    float a0 = 0.f, a1 = 0.f, a2 = 0.f, a3 = 0.f;
    float a4 = 0.f, a5 = 0.f, a6 = 0.f, a7 = 0.f;
    for (int k = 0; k < cnt; k += 8) {
        int4 ra = row[k >> 2];
        int4 rb = row[(k >> 2) + 1];
        int s0 = (k + 0 < cnt) ? ra.x : 0;   // clamp -> hot node-0 line
        int s1 = (k + 1 < cnt) ? ra.y : 0;
        int s2 = (k + 2 < cnt) ? ra.z : 0;
        int s3 = (k + 3 < cnt) ? ra.w : 0;
        int s4 = (k + 4 < cnt) ? rb.x : 0;
        int s5 = (k + 5 < cnt) ? rb.y : 0;
        int s6 = (k + 6 < cnt) ? rb.z : 0;
        int s7 = (k + 7 < cnt) ? rb.w : 0;
        float v0 = (float)h16[(long)s0 * DIM + d];   // 128B/wave, 1 line req
        float v1 = (float)h16[(long)s1 * DIM + d];
        float v2 = (float)h16[(long)s2 * DIM + d];
        float v3 = (float)h16[(long)s3 * DIM + d];
        float v4 = (float)h16[(long)s4 * DIM + d];
        float v5 = (float)h16[(long)s5 * DIM + d];
        float v6 = (float)h16[(long)s6 * DIM + d];
        float v7 = (float)h16[(long)s7 * DIM + d];
        a0 += (k + 0 < cnt) ? v0 : 0.f;
        a1 += (k + 1 < cnt) ? v1 : 0.f;
        a2 += (k + 2 < cnt) ? v2 : 0.f;
        a3 += (k + 3 < cnt) ? v3 : 0.f;
        a4 += (k + 4 < cnt) ? v4 : 0.f;
        a5 += (k + 5 < cnt) ? v5 : 0.f;
        a6 += (k + 6 < cnt) ? v6 : 0.f;
        a7 += (k + 7 < cnt) ? v7 : 0.f;
    }
    if (dval > CSR_CAP) {                 // rare overflow edges
        int m = min(*ovcnt, OV_CAP);
        for (int i = 0; i < m; ++i) {
            if (ovpairs[2 * i] == n) a0 += (float)h16[(long)ovpairs[2 * i + 1] * DIM + d];
        }
    }
    agg[(long)n * DIM + d] = own + ((a0 + a1) + (a2 + a3)) + ((a4 + a5) + (a6 + a7));
}

// ---------------------------------------------------------------------------
// out[n] = relu(in[n] @ W + b). 2 nodes x 32 dims per thread (R9 form,
// measured-best): 64 acc + light staging stays well under the VGPR cliff
// (R3/R11/R12 all spilled with heavier structures); sW reads are wave-uniform
// broadcasts (conflict-free).
// ---------------------------------------------------------------------------
__global__ __launch_bounds__(256) void mlp_gemm_kernel(
        const float* __restrict__ in, const float* __restrict__ W,
        const float* __restrict__ b, float* __restrict__ out) {
    __shared__ __align__(16) float sW[DIM * DIM];
    __shared__ float sb[DIM];
    for (int k = threadIdx.x; k < DIM * DIM / 4; k += 256)
        ((float4*)sW)[k] = ((const float4*)W)[k];
    if (threadIdx.x < DIM) sb[threadIdx.x] = b[threadIdx.x];
    __syncthreads();

    int p = threadIdx.x & 127;
    int j0 = (threadIdx.x >> 7) * 32;
    int base = blockIdx.x * 256;
    int n0 = base + p;
    int n1 = base + 128 + p;
    bool v1 = n1 < N_NODES;
    const float* inr0 = in + (long)n0 * DIM;
    const float* inr1 = in + (long)(v1 ? n1 : n0) * DIM;

    float acc0[32], acc1[32];
#pragma unroll
    for (int j = 0; j < 32; ++j) { acc0[j] = sb[j0 + j]; acc1[j] = acc0[j]; }

    for (int d4 = 0; d4 < DIM / 4; ++d4) {
        float4 za = ((const float4*)inr0)[d4];
        float4 zb = ((const float4*)inr1)[d4];
        const float* w0 = sW + (d4 * 4 + 0) * DIM + j0;
        const float* w1 = sW + (d4 * 4 + 1) * DIM + j0;
        const float* w2 = sW + (d4 * 4 + 2) * DIM + j0;
        const float* w3 = sW + (d4 * 4 + 3) * DIM + j0;
#pragma unroll
        for (int j = 0; j < 32; j += 4) {
            float4 a0 = *(const float4*)(w0 + j);
            float4 a1 = *(const float4*)(w1 + j);
            float4 a2 = *(const float4*)(w2 + j);
            float4 a3 = *(const float4*)(w3 + j);
            acc0[j + 0] += za.x * a0.x + za.y * a1.x + za.z * a2.x + za.w * a3.x;
            acc0[j + 1] += za.x * a0.y + za.y * a1.y + za.z * a2.y + za.w * a3.y;
            acc0[j + 2] += za.x * a0.z + za.y * a1.z + za.z * a2.z + za.w * a3.z;
            acc0[j + 3] += za.x * a0.w + za.y * a1.w + za.z * a2.w + za.w * a3.w;
            acc1[j + 0] += zb.x * a0.x + zb.y * a1.x + zb.z * a2.x + zb.w * a3.x;
            acc1[j + 1] += zb.x * a0.y + zb.y * a1.y + zb.z * a2.y + zb.w * a3.y;
            acc1[j + 2] += zb.x * a0.z + zb.y * a1.z + zb.z * a2.z + zb.w * a3.z;
            acc1[j + 3] += zb.x * a0.w + zb.y * a1.w + zb.z * a2.w + zb.w * a3.w;
        }
    }

    float* o0 = out + (long)n0 * DIM + j0;
#pragma unroll
    for (int j = 0; j < 32; j += 4) {
        float4 v = { fmaxf(acc0[j], 0.f), fmaxf(acc0[j + 1], 0.f),
                     fmaxf(acc0[j + 2], 0.f), fmaxf(acc0[j + 3], 0.f) };
        *(float4*)(o0 + j) = v;
    }
    if (v1) {
        float* o1 = out + (long)n1 * DIM + j0;
#pragma unroll
        for (int j = 0; j < 32; j += 4) {
            float4 v = { fmaxf(acc1[j], 0.f), fmaxf(acc1[j + 1], 0.f),
                         fmaxf(acc1[j + 2], 0.f), fmaxf(acc1[j + 3], 0.f) };
            *(float4*)(o1 + j) = v;
        }
    }
}

// ---------------------------------------------------------------------------
// BN stats: per-block partial (sum, sumsq) per dim, unrolled x8 (R15 lesson:
// keep 256 blocks — 1024 made the single-block finalize read 4x partials at
// cross-XCD miss latency, +70us; instead double in-flight rows per wave).
// ---------------------------------------------------------------------------
__global__ void stats_partial_kernel(const float* __restrict__ z, float* __restrict__ partials) {
    __shared__ float red[2 * 256];
    int d = threadIdx.x & 63;
    int slot = threadIdx.x >> 6;
    const int S = STATS_BLOCKS * 4;  // 1024
    float s1 = 0.f, s2 = 0.f;
    int n = blockIdx.x * 4 + slot;
    for (; n + 7 * S < N_NODES; n += 8 * S) {
        float v0 = z[(long)(n + 0 * S) * DIM + d];
        float v1 = z[(long)(n + 1 * S) * DIM + d];
        float v2 = z[(long)(n + 2 * S) * DIM + d];
        float v3 = z[(long)(n + 3 * S) * DIM + d];
        float v4 = z[(long)(n + 4 * S) * DIM + d];
        float v5 = z[(long)(n + 5 * S) * DIM + d];
        float v6 = z[(long)(n + 6 * S) * DIM + d];
        float v7 = z[(long)(n + 7 * S) * DIM + d];
        s1 += ((v0 + v1) + (v2 + v3)) + ((v4 + v5) + (v6 + v7));
        s2 += ((v0 * v0 + v1 * v1) + (v2 * v2 + v3 * v3))
            + ((v4 * v4 + v5 * v5) + (v6 * v6 + v7 * v7));
    }
    for (; n < N_NODES; n += S) {
        float v = z[(long)n * DIM + d];
        s1 += v;
        s2 += v * v;
    }
    red[threadIdx.x] = s1;
    red[256 + threadIdx.x] = s2;
    __syncthreads();
    if (threadIdx.x < 64) {
        float a = red[d] + red[64 + d] + red[128 + d] + red[192 + d];
        float c = red[256 + d] + red[320 + d] + red[384 + d] + red[448 + d];
        partials[blockIdx.x * 128 + d] = a;
        partials[blockIdx.x * 128 + 64 + d] = c;
    }
}

__global__ void stats_finalize_kernel(const float* __restrict__ partials,
                                      const float* __restrict__ gamma,
                                      const float* __restrict__ beta,
                                      float* __restrict__ ss) {
    __shared__ float r1[256], r2[256];
    int d = threadIdx.x & 63, q = threadIdx.x >> 6;
    float s1 = 0.f, s2 = 0.f;
    for (int b2_ = q; b2_ < STATS_BLOCKS; b2_ += 4) {
        s1 += partials[b2_ * 128 + d];
        s2 += partials[b2_ * 128 + 64 + d];
    }
    r1[threadIdx.x] = s1;
    r2[threadIdx.x] = s2;
    __syncthreads();
    if (threadIdx.x < 64) {
        s1 = r1[d] + r1[64 + d] + r1[128 + d] + r1[192 + d];
        s2 = r2[d] + r2[64 + d] + r2[128 + d] + r2[192 + d];
        float mu = s1 * (1.f / N_NODES);
        float var = s2 * (1.f / N_NODES) - mu * mu;
        float rs = 1.f / sqrtf(fmaxf(var, 0.f) + BN_EPS);
        float sc = gamma[d] * rs;
        ss[d] = sc;
        ss[64 + d] = beta[d] - mu * sc;
    }
}

// z_bn = z*scale + shift into xs slice (row stride 320) AND the fp16 gather
// copy for the next layer (h16 == nullptr on last layer).
__global__ void bn_apply_kernel(const float* __restrict__ z, const float* __restrict__ ss,
                                float* __restrict__ outxs, f16* __restrict__ h16) {
    long t = (long)blockIdx.x * 256 + threadIdx.x;
    if (t >= (long)N_NODES * (DIM / 4)) return;
    int r = (int)(t & 15);
    long n = t >> 4;
    float4 v = ((const float4*)(z + n * DIM))[r];
    float4 sc = ((const float4*)ss)[r];
    float4 sh = ((const float4*)(ss + DIM))[r];
    float4 o = { v.x * sc.x + sh.x, v.y * sc.y + sh.y,
                 v.z * sc.z + sh.z, v.w * sc.w + sh.w };
    ((float4*)(outxs + n * (DIM * NLAYERS)))[r] = o;
    if (h16) {
        f16x4 p = { (f16)o.x, (f16)o.y, (f16)o.z, (f16)o.w };
        *(f16x4*)(h16 + n * DIM + r * 4) = p;
    }
}

__global__ void graph_starts_kernel(const int* __restrict__ batch, int* __restrict__ starts) {
    int g = threadIdx.x;
    if (g > NUM_GRAPHS) return;
    int lo = 0, hi = N_NODES;
    while (lo < hi) {
        int mid = (lo + hi) >> 1;
        if (batch[mid] < g) lo = mid + 1; else hi = mid;
    }
    starts[g] = lo;
}

// Pool: block = (graph, layer-slice of 64 dims); 1280 one-wave blocks.
__global__ __launch_bounds__(64) void pool_kernel(
        const float* __restrict__ xs, const int* __restrict__ starts,
        float* __restrict__ outpool) {
    int g = blockIdx.x;
    int d = blockIdx.y * 64 + threadIdx.x;
    int s = starts[g], e = starts[g + 1];
    const int LD = DIM * NLAYERS;
    float a0 = 0.f, a1 = 0.f, a2 = 0.f, a3 = 0.f;
    float a4 = 0.f, a5 = 0.f, a6 = 0.f, a7 = 0.f;
    int n = s;
    for (; n + 8 <= e; n += 8) {
        a0 += xs[(long)(n + 0) * LD + d];
        a1 += xs[(long)(n + 1) * LD + d];
        a2 += xs[(long)(n + 2) * LD + d];
        a3 += xs[(long)(n + 3) * LD + d];
        a4 += xs[(long)(n + 4) * LD + d];
        a5 += xs[(long)(n + 5) * LD + d];
        a6 += xs[(long)(n + 6) * LD + d];
        a7 += xs[(long)(n + 7) * LD + d];
    }
    for (; n < e; ++n) a0 += xs[(long)n * LD + d];
    float acc = ((a0 + a1) + (a2 + a3)) + ((a4 + a5) + (a6 + a7));
    outpool[(long)g * LD + d] = acc / fmaxf((float)(e - s), 1.f);
}

// ---------------------------------------------------------------------------
static inline size_t rup(size_t x) { return (x + 255) & ~(size_t)255; }

extern "C" void kernel_launch(void* const* d_in, const int* in_sizes, int n_in,
                              void* d_out, int out_size, void* d_ws, size_t ws_size,
                              hipStream_t stream) {
    const float* x     = (const float*)d_in[0];
    const int*   ei    = (const int*)d_in[1];
    const int*   batch = (const int*)d_in[2];
    const float* W1    = (const float*)d_in[3];
    const float* b1    = (const float*)d_in[4];
    const float* W2    = (const float*)d_in[5];
    const float* b2    = (const float*)d_in[6];
    const float* gamma = (const float*)d_in[7];
    const float* beta  = (const float*)d_in[8];

    float* out      = (float*)d_out;
    float* out_pool = out;                                      // 256 x 320
    float* out_xs   = out + (size_t)NUM_GRAPHS * DIM * NLAYERS; // 100000 x 320

    char* w = (char*)d_ws;
    int*   csr      = (int*)w;    w += rup((size_t)N_NODES * CSR_CAP * 4);
    int*   cursor   = (int*)w;    w += rup((size_t)N_NODES * 4);
    int*   ovcnt    = (int*)w;    w += 256;
    int*   ovpairs  = (int*)w;    w += rup((size_t)OV_CAP * 8);
    float* agg      = (float*)w;  w += rup((size_t)N_NODES * DIM * 4);
    float* bufB     = (float*)w;  w += rup((size_t)N_NODES * DIM * 4);
    f16*   h16      = (f16*)w;    w += rup((size_t)N_NODES * DIM * 2);
    float* partials = (float*)w;  w += rup((size_t)STATS_BLOCKS * 128 * 4);
    float* ss       = (float*)w;  w += 512;
    int*   starts   = (int*)w;    w += rup((size_t)(NUM_GRAPHS + 1) * 4);
    float* zbuf     = agg;        // gemm2 output reuses agg

    hipMemsetAsync(cursor, 0, (size_t)N_NODES * 4, stream);
    hipMemsetAsync(ovcnt, 0, 4, stream);
    for (int sh = 0; sh < NSHARD; ++sh) {
        build_csr_shard_kernel<<<(N_EDGES + 255) / 256, 256, 0, stream>>>(
            ei, cursor, csr, ovcnt, ovpairs, sh * SHARD_W, (sh + 1) * SHARD_W);
    }
    cast_x_kernel<<<((long)N_NODES * DIM / 4 + 255) / 256, 256, 0, stream>>>(x, h16);
    graph_starts_kernel<<<1, 320, 0, stream>>>(batch, starts);

    const float* hself = x;
    int hs = DIM;
    for (int l = 0; l < NLAYERS; ++l) {
        // agg = hself + neighbor-sum(h16)   (f32 accum, fp16 gather, 1 node/wave)
        aggregate_f16_kernel<<<((long)N_NODES * DIM + 255) / 256, 256, 0, stream>>>(
            csr, cursor, ovcnt, ovpairs, h16, hself, hs, agg);
        // bufB = relu(agg @ W1 + b1)
        mlp_gemm_kernel<<<NBLK, 256, 0, stream>>>(
            agg, W1 + (size_t)l * DIM * DIM, b1 + (size_t)l * DIM, bufB);
        // zbuf = relu(bufB @ W2 + b2)   (overwrites agg)
        mlp_gemm_kernel<<<NBLK, 256, 0, stream>>>(
            bufB, W2 + (size_t)l * DIM * DIM, b2 + (size_t)l * DIM, zbuf);
        stats_partial_kernel<<<STATS_BLOCKS, 256, 0, stream>>>(zbuf, partials);
        stats_finalize_kernel<<<1, 256, 0, stream>>>(partials, gamma + (size_t)l * DIM,
                                                     beta + (size_t)l * DIM, ss);
        bn_apply_kernel<<<((long)N_NODES * (DIM / 4) + 255) / 256, 256, 0, stream>>>(
            zbuf, ss, out_xs + (size_t)l * DIM, (l + 1 < NLAYERS) ? h16 : nullptr);
        hself = out_xs + (size_t)l * DIM;
        hs = DIM * NLAYERS;
    }

    pool_kernel<<<dim3(NUM_GRAPHS, NLAYERS), 64, 0, stream>>>(out_xs, starts, out_pool);
}